// Round 3
// baseline (240.322 us; speedup 1.0000x reference)
//
#include <hip/hip_runtime.h>
#include <hip/hip_bf16.h>
#include <cstdint>

// Problem constants
#define LL 3
#define NN 512
#define DD 1024
#define HH 4096
#define SS 24576    // B*N*L tokens
#define LNTOK 1536  // L*N tokens per batch
#define CAP 8192    // ceil(S/E)

// ws offsets in 4-byte words (total 132032 words = 528 KB; <= 565 KB proven)
#define OFF_HIST    0       // int[96*3] pad 320
#define OFF_CBASE   320     // int[96*3] pad 320
#define OFF_GSUM    640     // float[3] pad 64
#define OFF_GBE     704     // float[16*3] pad 64
#define OFF_CNTB    768     // float[16] pad 64
#define OFF_NDROP   832     // int[1] pad 128
#define OFF_Z       960     // float[16*3*1024]
#define OFF_YS      50112   // float[16*1024]
#define OFF_ZEROEND 66496   // everything below here is zeroed each call
#define OFF_IDX     66496   // int[S]
#define OFF_GVAL    91072   // float[S]
#define OFF_DROP    115648  // int[16384]
#define OFF_END     132032

// ---------------------------------------------------------------------------
// K1: fused gating + unconditional z accumulation. grid 1536 x 256.
// Block = 16 tokens (same b, same 256-chunk). Wave = 4 tokens, prefetch depth 1.
__global__ __launch_bounds__(256, 4) void k1_fused(const float* __restrict__ x,
                                                   const float* __restrict__ wg,
                                                   int* __restrict__ idx,
                                                   float* __restrict__ gval,
                                                   int* __restrict__ hist,
                                                   float* __restrict__ gsum,
                                                   float* __restrict__ gbe,
                                                   float* __restrict__ z) {
  __shared__ float wgT[3][1024];
  __shared__ float zp[3][1024];
  __shared__ float sG[3], sB[3];
  __shared__ int sH[3];
  int tid = threadIdx.x;
  for (int i = tid; i < 3072; i += 256) {
    wgT[i % 3][i / 3] = wg[i];
    ((float*)zp)[i] = 0.f;
  }
  if (tid < 3) { sG[tid] = 0.f; sB[tid] = 0.f; sH[tid] = 0; }
  __syncthreads();
  int lane = tid & 63, w = tid >> 6;
  int t0 = blockIdx.x * 16;
  int b = t0 / LNTOK;        // uniform: 16 | 1536
  int chunk = t0 >> 8;       // uniform: 16 | 256
  int tbase = t0 + w * 4;
  float a0[16], a1[16], a2[16];
#pragma unroll
  for (int j = 0; j < 16; ++j) { a0[j] = 0.f; a1[j] = 0.f; a2[j] = 0.f; }
  float lg0 = 0, lg1 = 0, lg2 = 0, lb0 = 0, lb1 = 0, lb2 = 0;
  int lh0 = 0, lh1 = 0, lh2 = 0;
  float4 cur[4], nxt[4];
  {
    int r = tbase % LNTOK;
    int n = r / LL, l = r % LL;
    const float* row = x + (size_t)((b * LL + l) * NN + n) * DD + lane * 4;
#pragma unroll
    for (int q = 0; q < 4; ++q) cur[q] = *(const float4*)(row + q * 256);
  }
#pragma unroll
  for (int k = 0; k < 4; ++k) {
    if (k < 3) {  // prefetch next token's row
      int r = (tbase + k + 1) % LNTOK;
      int n = r / LL, l = r % LL;
      const float* row = x + (size_t)((b * LL + l) * NN + n) * DD + lane * 4;
#pragma unroll
      for (int q = 0; q < 4; ++q) nxt[q] = *(const float4*)(row + q * 256);
    }
    float d0 = 0, d1 = 0, d2 = 0;
#pragma unroll
    for (int q = 0; q < 4; ++q) {
      int dd = q * 256 + lane * 4;
      float4 w0 = *(const float4*)(&wgT[0][dd]);
      float4 w1 = *(const float4*)(&wgT[1][dd]);
      float4 w2 = *(const float4*)(&wgT[2][dd]);
      d0 += cur[q].x * w0.x + cur[q].y * w0.y + cur[q].z * w0.z + cur[q].w * w0.w;
      d1 += cur[q].x * w1.x + cur[q].y * w1.y + cur[q].z * w1.z + cur[q].w * w1.w;
      d2 += cur[q].x * w2.x + cur[q].y * w2.y + cur[q].z * w2.z + cur[q].w * w2.w;
    }
#pragma unroll
    for (int off = 32; off; off >>= 1) {
      d0 += __shfl_xor(d0, off);
      d1 += __shfl_xor(d1, off);
      d2 += __shfl_xor(d2, off);
    }
    float m = d0; int id = 0;
    if (d1 > m) { m = d1; id = 1; }
    if (d2 > m) { m = d2; id = 2; }
    float e0 = expf(d0 - m), e1 = expf(d1 - m), e2 = expf(d2 - m);
    float inv = 1.0f / (e0 + e1 + e2);   // gate prob of argmax expert
    if (lane == 0) {
      int t = tbase + k;
      idx[t] = id;
      gval[t] = inv;
      lg0 += e0 * inv; lg1 += e1 * inv; lg2 += e2 * inv;
      if (id == 0) { lh0++; lb0 += inv; }
      else if (id == 1) { lh1++; lb1 += inv; }
      else { lh2++; lb2 += inv; }
    }
    if (id == 0) {         // id is wave-uniform
#pragma unroll
      for (int q = 0; q < 4; ++q) {
        a0[q * 4 + 0] += inv * cur[q].x; a0[q * 4 + 1] += inv * cur[q].y;
        a0[q * 4 + 2] += inv * cur[q].z; a0[q * 4 + 3] += inv * cur[q].w;
      }
    } else if (id == 1) {
#pragma unroll
      for (int q = 0; q < 4; ++q) {
        a1[q * 4 + 0] += inv * cur[q].x; a1[q * 4 + 1] += inv * cur[q].y;
        a1[q * 4 + 2] += inv * cur[q].z; a1[q * 4 + 3] += inv * cur[q].w;
      }
    } else {
#pragma unroll
      for (int q = 0; q < 4; ++q) {
        a2[q * 4 + 0] += inv * cur[q].x; a2[q * 4 + 1] += inv * cur[q].y;
        a2[q * 4 + 2] += inv * cur[q].z; a2[q * 4 + 3] += inv * cur[q].w;
      }
    }
#pragma unroll
    for (int q = 0; q < 4; ++q) cur[q] = nxt[q];
  }
  if (lane == 0) {
    atomicAdd(&sG[0], lg0); atomicAdd(&sG[1], lg1); atomicAdd(&sG[2], lg2);
    atomicAdd(&sB[0], lb0); atomicAdd(&sB[1], lb1); atomicAdd(&sB[2], lb2);
    atomicAdd(&sH[0], lh0); atomicAdd(&sH[1], lh1); atomicAdd(&sH[2], lh2);
  }
#pragma unroll
  for (int q = 0; q < 4; ++q) {
    int dd = q * 256 + lane * 4;
#pragma unroll
    for (int j = 0; j < 4; ++j) {
      atomicAdd(&zp[0][dd + j], a0[q * 4 + j]);
      atomicAdd(&zp[1][dd + j], a1[q * 4 + j]);
      atomicAdd(&zp[2][dd + j], a2[q * 4 + j]);
    }
  }
  __syncthreads();
  if (tid < 3) {
    atomicAdd(&gsum[tid], sG[tid]);
    atomicAdd(&gbe[b * 3 + tid], sB[tid]);
    atomicAdd(&hist[chunk * 3 + tid], sH[tid]);
  }
  for (int i = tid; i < 3072; i += 256)
    atomicAdd(&z[(size_t)b * 3072 + i], ((float*)zp)[i]);
}

// ---------------------------------------------------------------------------
// K2: mask count + chunk prefix scan + l_aux. 1 block x 256.
__global__ __launch_bounds__(256) void k2_mid(const void* __restrict__ maskp,
                                              const int* __restrict__ hist,
                                              int* __restrict__ cbase,
                                              const float* __restrict__ gsum,
                                              float* __restrict__ cntb,
                                              float* __restrict__ laux_out) {
  __shared__ int det;
  __shared__ int scnt[16];
  __shared__ int sh[288];
  int tid = threadIdx.x;
  if (tid == 0) det = 0;
  if (tid < 16) scnt[tid] = 0;
  for (int i = tid; i < 288; i += 256) sh[i] = hist[i];
  __syncthreads();
  const uint32_t* mw = (const uint32_t*)maskp;
  for (int i = tid; i < LNTOK; i += 256) {   // sniff encoding
    uint32_t v = mw[i];
    if (v == 0x3F800000u) det = 2;   // float32
    else if (v > 1u) det = 1;        // packed bool bytes
  }
  __syncthreads();
  if (det == 1) {
    const uint8_t* mb = (const uint8_t*)maskp;
    for (int i = tid; i < SS; i += 256)
      if (mb[i] == 0) atomicAdd(&scnt[i / LNTOK], 1);
  } else {
    for (int i = tid; i < SS; i += 256)
      if (mw[i] == 0) atomicAdd(&scnt[i / LNTOK], 1);
  }
  __syncthreads();
  if (tid < 16) { int c = scnt[tid]; cntb[tid] = (float)(c < 1 ? 1 : c); }
  if (tid < 96) {
    int s0 = 0, s1 = 0, s2 = 0;
    for (int c = 0; c < tid; ++c) { s0 += sh[c * 3]; s1 += sh[c * 3 + 1]; s2 += sh[c * 3 + 2]; }
    cbase[tid * 3 + 0] = s0; cbase[tid * 3 + 1] = s1; cbase[tid * 3 + 2] = s2;
  }
  if (tid == 0) {
    int r0 = 0, r1 = 0, r2 = 0;
    for (int c = 0; c < 96; ++c) { r0 += sh[c * 3]; r1 += sh[c * 3 + 1]; r2 += sh[c * 3 + 2]; }
    float invS = 1.0f / (float)SS;
    *laux_out = 3.0f * (gsum[0] * invS * ((float)r0 * invS) +
                        gsum[1] * invS * ((float)r1 * invS) +
                        gsum[2] * invS * ((float)r2 * invS));
  }
}

// ---------------------------------------------------------------------------
// K3a: find dropped tokens (pos >= CAP), append to compact list, fix gbe.
// grid 96 x 256 (one 256-token chunk per block); early-exit if chunk can't overflow.
__global__ __launch_bounds__(256) void k3a_drops(const int* __restrict__ idx,
                                                 const float* __restrict__ gval,
                                                 const int* __restrict__ cbase,
                                                 float* __restrict__ gbe,
                                                 int* __restrict__ drop,
                                                 int* __restrict__ ndrop) {
  int cb0 = cbase[blockIdx.x * 3 + 0];
  int cb1 = cbase[blockIdx.x * 3 + 1];
  int cb2 = cbase[blockIdx.x * 3 + 2];
  if (cb0 <= CAP - 256 && cb1 <= CAP - 256 && cb2 <= CAP - 256) return;
  __shared__ int whist[4][3];
  int tid = threadIdx.x;
  int t = blockIdx.x * 256 + tid;
  int e = idx[t];
  float gv = gval[t];
  int lane = tid & 63, w = tid >> 6;
  unsigned long long m0 = __ballot(e == 0);
  unsigned long long m1 = __ballot(e == 1);
  unsigned long long m2 = __ballot(e == 2);
  if (lane == 0) {
    whist[w][0] = __popcll(m0);
    whist[w][1] = __popcll(m1);
    whist[w][2] = __popcll(m2);
  }
  __syncthreads();
  int pre = 0;
  for (int ww = 0; ww < 3; ++ww)
    if (ww < w) pre += whist[ww][e];
  unsigned long long lt = (1ull << lane) - 1ull;
  unsigned long long me = (e == 0) ? m0 : (e == 1) ? m1 : m2;
  int cb = (e == 0) ? cb0 : (e == 1) ? cb1 : cb2;
  int pos = cb + pre + __popcll(me & lt);
  bool dropf = (pos >= CAP);
  unsigned long long db = __ballot(dropf);
  if (db) {
    int base = 0;
    if (lane == 0) base = atomicAdd(ndrop, __popcll(db));
    base = __shfl(base, 0);
    if (dropf) {
      int rank = __popcll(db & lt);
      int b = t / LNTOK;
      drop[base + rank] = t | (e << 20);
      atomicAdd(&gbe[b * 3 + e], -gv);
    }
  }
}

// ---------------------------------------------------------------------------
// K3b: z[b,e,:] -= g*x[t] for each dropped token; load-balanced over grid.
__global__ __launch_bounds__(256) void k3b_sub(const float* __restrict__ x,
                                               const float* __restrict__ gval,
                                               const int* __restrict__ drop,
                                               const int* __restrict__ ndrop,
                                               float* __restrict__ z) {
  int nd = *ndrop;
  for (int i = blockIdx.x; i < nd; i += gridDim.x) {
    int ent = drop[i];
    int t = ent & 0xFFFFF;
    int e = ent >> 20;
    int b = t / LNTOK;
    int r = t % LNTOK;
    int n = r / LL, l = r % LL;
    float g = gval[t];
    const float* row = x + (size_t)((b * LL + l) * NN + n) * DD;
    float* zr = z + (size_t)b * 3072 + e * 1024;
    int d = threadIdx.x * 4;
    float4 v = *(const float4*)(row + d);
    atomicAdd(&zr[d + 0], -g * v.x);
    atomicAdd(&zr[d + 1], -g * v.y);
    atomicAdd(&zr[d + 2], -g * v.z);
    atomicAdd(&zr[d + 3], -g * v.w);
  }
}

// ---------------------------------------------------------------------------
// K4: ys += z[16,3072] @ We[3072,1024]. grid 384 = 16 n-tiles(64) x 24 k-chunks(128).
__global__ __launch_bounds__(256) void k4_we(const float* __restrict__ z,
                                             const float* __restrict__ We,
                                             float* __restrict__ ys) {
  __shared__ float zt[16][128];
  __shared__ float Ct[16][64];
  int tid = threadIdx.x;
  int nt = blockIdx.x & 15, ks = blockIdx.x >> 4;
  int n0 = nt * 64, k0 = ks * 128;
  for (int i = tid; i < 2048; i += 256)
    zt[i >> 7][i & 127] = z[(i >> 7) * 3072 + k0 + (i & 127)];
  for (int i = tid; i < 1024; i += 256) ((float*)Ct)[i] = 0.f;
  __syncthreads();
  int nl = tid & 63, kg = tid >> 6;
  float acc[16];
#pragma unroll
  for (int m = 0; m < 16; ++m) acc[m] = 0.f;
  const float* wp = We + (size_t)k0 * 1024 + n0 + nl;
#pragma unroll 4
  for (int kk = kg * 32; kk < kg * 32 + 32; ++kk) {
    float bv = wp[(size_t)kk * 1024];
#pragma unroll
    for (int m = 0; m < 16; ++m) acc[m] += zt[m][kk] * bv;
  }
#pragma unroll
  for (int m = 0; m < 16; ++m) atomicAdd(&Ct[m][nl], acc[m]);
  __syncthreads();
  for (int i = tid; i < 1024; i += 256)
    atomicAdd(&ys[(i >> 6) * 1024 + n0 + (i & 63)], ((float*)Ct)[i]);
}

// ---------------------------------------------------------------------------
// K5: out[b,h] = ((ys+bias)[16,1024] @ Wp[1024,4096] + 1536*bp) / cnt.
// grid 512 = 64 h-tiles(64) x 8 k-chunks(128). out pre-zeroed by memset.
__global__ __launch_bounds__(256) void k5_out(const float* __restrict__ ys,
                                              const float* __restrict__ Wp,
                                              const float* __restrict__ be,
                                              const float* __restrict__ gbe,
                                              const float* __restrict__ bp,
                                              const float* __restrict__ cntb,
                                              float* __restrict__ out) {
  __shared__ float yt[16][128];
  __shared__ float Ct[16][64];
  __shared__ float sgbe[48];
  __shared__ float sinv[16];
  int tid = threadIdx.x;
  int ht = blockIdx.x & 63, ks = blockIdx.x >> 6;
  int n0 = ht * 64, k0 = ks * 128;
  if (tid < 48) sgbe[tid] = gbe[tid];
  if (tid < 16) sinv[tid] = 1.0f / cntb[tid];
  __syncthreads();
  for (int i = tid; i < 2048; i += 256) {
    int m = i >> 7, kk = i & 127;
    int k = k0 + kk;
    yt[m][kk] = ys[m * 1024 + k] + sgbe[m * 3 + 0] * be[k] +
                sgbe[m * 3 + 1] * be[1024 + k] + sgbe[m * 3 + 2] * be[2048 + k];
  }
  for (int i = tid; i < 1024; i += 256) ((float*)Ct)[i] = 0.f;
  __syncthreads();
  int nl = tid & 63, kg = tid >> 6;
  float acc[16];
#pragma unroll
  for (int m = 0; m < 16; ++m) acc[m] = 0.f;
  const float* wpp = Wp + (size_t)k0 * HH + n0 + nl;
#pragma unroll 4
  for (int kk = kg * 32; kk < kg * 32 + 32; ++kk) {
    float bv = wpp[(size_t)kk * HH];
#pragma unroll
    for (int m = 0; m < 16; ++m) acc[m] += yt[m][kk] * bv;
  }
#pragma unroll
  for (int m = 0; m < 16; ++m) atomicAdd(&Ct[m][nl], acc[m]);
  __syncthreads();
  for (int i = tid; i < 1024; i += 256) {
    int m = i >> 6, h = i & 63;
    float v = ((float*)Ct)[i];
    if (ks == 0) v += 1536.0f * bp[n0 + h];
    atomicAdd(&out[(size_t)m * HH + n0 + h], v * sinv[m]);
  }
}

// ---------------------------------------------------------------------------
extern "C" void kernel_launch(void* const* d_in, const int* in_sizes, int n_in,
                              void* d_out, int out_size, void* d_ws, size_t ws_size,
                              hipStream_t stream) {
  const float* x    = (const float*)d_in[0];
  const void*  mask = d_in[1];
  const float* wg   = (const float*)d_in[2];
  const float* We   = (const float*)d_in[3];
  const float* be   = (const float*)d_in[4];
  const float* Wp   = (const float*)d_in[5];
  const float* bp   = (const float*)d_in[6];
  float* out = (float*)d_out;
  float* wsf = (float*)d_ws;
  int*   wsi = (int*)d_ws;

  // zero atomic targets + z + ys (ws/out are not re-poisoned between replays)
  hipMemsetAsync(d_ws, 0, (size_t)OFF_ZEROEND * 4, stream);
  hipMemsetAsync(d_out, 0, (size_t)out_size * 4, stream);

  k1_fused<<<1536, 256, 0, stream>>>(x, wg, wsi + OFF_IDX, wsf + OFF_GVAL,
                                     wsi + OFF_HIST, wsf + OFF_GSUM,
                                     wsf + OFF_GBE, wsf + OFF_Z);
  k2_mid<<<1, 256, 0, stream>>>(mask, wsi + OFF_HIST, wsi + OFF_CBASE,
                                wsf + OFF_GSUM, wsf + OFF_CNTB, out + 65536);
  k3a_drops<<<96, 256, 0, stream>>>(wsi + OFF_IDX, wsf + OFF_GVAL,
                                    wsi + OFF_CBASE, wsf + OFF_GBE,
                                    wsi + OFF_DROP, wsi + OFF_NDROP);
  k3b_sub<<<128, 256, 0, stream>>>(x, wsf + OFF_GVAL, wsi + OFF_DROP,
                                   wsi + OFF_NDROP, wsf + OFF_Z);
  k4_we<<<384, 256, 0, stream>>>(wsf + OFF_Z, We, wsf + OFF_YS);
  k5_out<<<512, 256, 0, stream>>>(wsf + OFF_YS, Wp, be, wsf + OFF_GBE, bp,
                                  wsf + OFF_CNTB, out);
}

// Round 4
// 196.681 us; speedup vs baseline: 1.2219x; 1.2219x over previous
//
#include <hip/hip_runtime.h>
#include <hip/hip_bf16.h>
#include <cstdint>

// Problem constants
#define LL 3
#define NN 512
#define DD 1024
#define HH 4096
#define SS 24576    // B*N*L tokens
#define LNTOK 1536  // L*N tokens per batch
#define CAP 8192    // ceil(S/E)

// ws offsets in 4-byte words (528 KB total; ws >= 565 KB proven in round 1)
#define OFF_HIST    0       // int[96*3] pad 320
#define OFF_GSUM    640     // float[3] pad 64
#define OFF_GBE     704     // float[16*3] pad 64
#define OFF_CNTI    768     // int[16] pad 64
#define OFF_NDROP   832     // int[1] pad 128
#define OFF_Z       960     // float[16*3*1024]
#define OFF_YS      50112   // float[16*1024]
#define OFF_ZEROEND 66496   // everything below here is zeroed each call
#define OFF_IDX     66496   // int[S]
#define OFF_GVAL    91072   // float[S]
#define OFF_DROP    115648  // int[16384]
#define OFF_END     132032

// ---------------------------------------------------------------------------
// K0: mask zero-count per batch (ballot). grid 96 x 256.
__global__ __launch_bounds__(256) void k0_mask(const void* __restrict__ maskp,
                                               int* __restrict__ cnti) {
  __shared__ int det;
  __shared__ int scnt;
  int tid = threadIdx.x;
  if (tid == 0) { det = 0; scnt = 0; }
  __syncthreads();
  const uint32_t* mw = (const uint32_t*)maskp;
  for (int i = tid; i < LNTOK; i += 256) {   // sniff encoding
    uint32_t v = mw[i];
    if (v == 0x3F800000u) det = 2;   // float32 0/1
    else if (v > 1u) det = 1;        // packed bool bytes
  }
  __syncthreads();
  int t = blockIdx.x * 256 + tid;
  int zero;
  if (det == 1) zero = (((const uint8_t*)maskp)[t] == 0);
  else          zero = (mw[t] == 0);
  unsigned long long bal = __ballot(zero);
  if ((tid & 63) == 0) atomicAdd(&scnt, __popcll(bal));
  __syncthreads();
  if (tid == 0) atomicAdd(&cnti[blockIdx.x / 6], scnt);  // 6 blocks per batch
}

// ---------------------------------------------------------------------------
// K1: fused gating + z accumulation, shuffle-free (LDS transpose-reduce).
// grid 768 x 256. Block = 32 tokens (uniform b, uniform 256-chunk).
__global__ __launch_bounds__(256, 3) void k1_fused(const float* __restrict__ x,
                                                   const float* __restrict__ wg,
                                                   int* __restrict__ idx,
                                                   float* __restrict__ gval,
                                                   int* __restrict__ hist,
                                                   float* __restrict__ gsum,
                                                   float* __restrict__ gbe,
                                                   float* __restrict__ z) {
  __shared__ float wgT[3][1024];     // 12 KB
  __shared__ float zp[3][1024];      // 12 KB
  __shared__ float part[32 * 195];   // [tok][e][65 padded] = 24.4 KB
  __shared__ float sd[104];
  __shared__ float sg[32];
  __shared__ int   se[32];
  __shared__ float sG[3], sB[3];
  __shared__ int   sH[3];
  int tid = threadIdx.x, lane = tid & 63, w = tid >> 6;
  for (int i = tid; i < 3072; i += 256) {
    wgT[i % 3][i / 3] = wg[i];
    ((float*)zp)[i] = 0.f;
  }
  if (tid < 3) { sG[tid] = 0.f; sB[tid] = 0.f; sH[tid] = 0; }
  __syncthreads();
  int t0 = blockIdx.x * 32;
  int b = t0 / LNTOK;          // uniform: 32 | 1536
  int chunk = t0 >> 8;         // uniform: 32 | 256

  // ---- Phase A: partial dots -> LDS (no cross-lane ops) ----
#pragma unroll
  for (int k = 0; k < 8; ++k) {
    int tok = w * 8 + k;
    int r = (t0 + tok) % LNTOK;
    int n = r / LL, l = r % LL;
    const float* row = x + (size_t)((b * LL + l) * NN + n) * DD + lane * 4;
    float4 v0 = *(const float4*)(row);
    float4 v1 = *(const float4*)(row + 256);
    float4 v2 = *(const float4*)(row + 512);
    float4 v3 = *(const float4*)(row + 768);
    float d0 = 0, d1 = 0, d2 = 0;
    {
      int dd = lane * 4;
      const float4 w00 = *(const float4*)(&wgT[0][dd]);
      const float4 w01 = *(const float4*)(&wgT[0][dd + 256]);
      const float4 w02 = *(const float4*)(&wgT[0][dd + 512]);
      const float4 w03 = *(const float4*)(&wgT[0][dd + 768]);
      d0 = v0.x * w00.x + v0.y * w00.y + v0.z * w00.z + v0.w * w00.w +
           v1.x * w01.x + v1.y * w01.y + v1.z * w01.z + v1.w * w01.w +
           v2.x * w02.x + v2.y * w02.y + v2.z * w02.z + v2.w * w02.w +
           v3.x * w03.x + v3.y * w03.y + v3.z * w03.z + v3.w * w03.w;
      const float4 w10 = *(const float4*)(&wgT[1][dd]);
      const float4 w11 = *(const float4*)(&wgT[1][dd + 256]);
      const float4 w12 = *(const float4*)(&wgT[1][dd + 512]);
      const float4 w13 = *(const float4*)(&wgT[1][dd + 768]);
      d1 = v0.x * w10.x + v0.y * w10.y + v0.z * w10.z + v0.w * w10.w +
           v1.x * w11.x + v1.y * w11.y + v1.z * w11.z + v1.w * w11.w +
           v2.x * w12.x + v2.y * w12.y + v2.z * w12.z + v2.w * w12.w +
           v3.x * w13.x + v3.y * w13.y + v3.z * w13.z + v3.w * w13.w;
      const float4 w20 = *(const float4*)(&wgT[2][dd]);
      const float4 w21 = *(const float4*)(&wgT[2][dd + 256]);
      const float4 w22 = *(const float4*)(&wgT[2][dd + 512]);
      const float4 w23 = *(const float4*)(&wgT[2][dd + 768]);
      d2 = v0.x * w20.x + v0.y * w20.y + v0.z * w20.z + v0.w * w20.w +
           v1.x * w21.x + v1.y * w21.y + v1.z * w21.z + v1.w * w21.w +
           v2.x * w22.x + v2.y * w22.y + v2.z * w22.z + v2.w * w22.w +
           v3.x * w23.x + v3.y * w23.y + v3.z * w23.z + v3.w * w23.w;
    }
    part[tok * 195 + lane] = d0;
    part[tok * 195 + 65 + lane] = d1;
    part[tok * 195 + 130 + lane] = d2;
  }
  __syncthreads();

  // ---- Phase B: parallel 64-way sums (96 threads, conflict-free) ----
  if (tid < 96) {
    const float* p = part + tid * 65;   // tok*195 + e*65 == tid*65
    float s0 = 0, s1 = 0, s2 = 0, s3 = 0;
#pragma unroll
    for (int l = 0; l < 64; l += 4) {
      s0 += p[l]; s1 += p[l + 1]; s2 += p[l + 2]; s3 += p[l + 3];
    }
    sd[tid] = (s0 + s1) + (s2 + s3);
  }
  __syncthreads();

  // ---- Phase B2: softmax/argmax for 32 tokens in parallel ----
  if (tid < 32) {
    float d0 = sd[tid * 3], d1 = sd[tid * 3 + 1], d2 = sd[tid * 3 + 2];
    float m = d0; int id = 0;
    if (d1 > m) { m = d1; id = 1; }
    if (d2 > m) { m = d2; id = 2; }
    float e0 = expf(d0 - m), e1 = expf(d1 - m), e2 = expf(d2 - m);
    float inv = 1.0f / (e0 + e1 + e2);   // gate prob of argmax expert
    int t = t0 + tid;
    idx[t] = id;
    gval[t] = inv;
    sg[tid] = inv;
    se[tid] = id;
    atomicAdd(&sG[0], e0 * inv);
    atomicAdd(&sG[1], e1 * inv);
    atomicAdd(&sG[2], e2 * inv);
    atomicAdd(&sB[id], inv);
    atomicAdd(&sH[id], 1);
  }
  __syncthreads();

  // ---- Phase C: z accumulation, gates known; x reload hits L2/L3 ----
  float a0[16], a1[16], a2[16];
#pragma unroll
  for (int j = 0; j < 16; ++j) { a0[j] = 0.f; a1[j] = 0.f; a2[j] = 0.f; }
#pragma unroll
  for (int k = 0; k < 8; ++k) {
    int tok = w * 8 + k;
    float g = sg[tok];      // LDS broadcast, wave-uniform
    int e = se[tok];        // wave-uniform
    int r = (t0 + tok) % LNTOK;
    int n = r / LL, l = r % LL;
    const float* row = x + (size_t)((b * LL + l) * NN + n) * DD + lane * 4;
    float4 v0 = *(const float4*)(row);
    float4 v1 = *(const float4*)(row + 256);
    float4 v2 = *(const float4*)(row + 512);
    float4 v3 = *(const float4*)(row + 768);
    if (e == 0) {
      a0[0] += g * v0.x;  a0[1] += g * v0.y;  a0[2] += g * v0.z;  a0[3] += g * v0.w;
      a0[4] += g * v1.x;  a0[5] += g * v1.y;  a0[6] += g * v1.z;  a0[7] += g * v1.w;
      a0[8] += g * v2.x;  a0[9] += g * v2.y;  a0[10] += g * v2.z; a0[11] += g * v2.w;
      a0[12] += g * v3.x; a0[13] += g * v3.y; a0[14] += g * v3.z; a0[15] += g * v3.w;
    } else if (e == 1) {
      a1[0] += g * v0.x;  a1[1] += g * v0.y;  a1[2] += g * v0.z;  a1[3] += g * v0.w;
      a1[4] += g * v1.x;  a1[5] += g * v1.y;  a1[6] += g * v1.z;  a1[7] += g * v1.w;
      a1[8] += g * v2.x;  a1[9] += g * v2.y;  a1[10] += g * v2.z; a1[11] += g * v2.w;
      a1[12] += g * v3.x; a1[13] += g * v3.y; a1[14] += g * v3.z; a1[15] += g * v3.w;
    } else {
      a2[0] += g * v0.x;  a2[1] += g * v0.y;  a2[2] += g * v0.z;  a2[3] += g * v0.w;
      a2[4] += g * v1.x;  a2[5] += g * v1.y;  a2[6] += g * v1.z;  a2[7] += g * v1.w;
      a2[8] += g * v2.x;  a2[9] += g * v2.y;  a2[10] += g * v2.z; a2[11] += g * v2.w;
      a2[12] += g * v3.x; a2[13] += g * v3.y; a2[14] += g * v3.z; a2[15] += g * v3.w;
    }
  }
  // ---- Phase D: fold into LDS, then staggered global atomics ----
#pragma unroll
  for (int q = 0; q < 4; ++q) {
    int dd = q * 256 + lane * 4;
#pragma unroll
    for (int j = 0; j < 4; ++j) {
      atomicAdd(&zp[0][dd + j], a0[q * 4 + j]);
      atomicAdd(&zp[1][dd + j], a1[q * 4 + j]);
      atomicAdd(&zp[2][dd + j], a2[q * 4 + j]);
    }
  }
  __syncthreads();
  if (tid < 3) {
    atomicAdd(&gsum[tid], sG[tid]);
    atomicAdd(&gbe[b * 3 + tid], sB[tid]);
    atomicAdd(&hist[chunk * 3 + tid], sH[tid]);
  }
  int shift = (blockIdx.x % 48) * 64;   // de-contend concurrent blocks
  for (int i = tid; i < 3072; i += 256) {
    int j = i + shift; if (j >= 3072) j -= 3072;
    atomicAdd(&z[(size_t)b * 3072 + j], ((float*)zp)[j]);
  }
}

// ---------------------------------------------------------------------------
// K3a: per-chunk prefix from hist, find dropped tokens, fix gbe; block 95
// also emits l_aux. grid 96 x 256.
__global__ __launch_bounds__(256) void k3a_drops(const int* __restrict__ idx,
                                                 const float* __restrict__ gval,
                                                 const int* __restrict__ hist,
                                                 const float* __restrict__ gsum,
                                                 float* __restrict__ gbe,
                                                 int* __restrict__ drop,
                                                 int* __restrict__ ndrop,
                                                 float* __restrict__ laux_out) {
  __shared__ int sh[288];
  __shared__ int scb[3];
  __shared__ int whist[4][3];
  int tid = threadIdx.x;
  for (int i = tid; i < 288; i += 256) sh[i] = hist[i];
  __syncthreads();
  if (tid < 3) {
    int s = 0;
    for (int c = 0; c < (int)blockIdx.x; ++c) s += sh[c * 3 + tid];
    scb[tid] = s;
  }
  __syncthreads();
  if (blockIdx.x == 95 && tid == 0) {
    int r0 = scb[0] + sh[285], r1 = scb[1] + sh[286], r2 = scb[2] + sh[287];
    float invS = 1.0f / (float)SS;
    *laux_out = 3.0f * (gsum[0] * invS * ((float)r0 * invS) +
                        gsum[1] * invS * ((float)r1 * invS) +
                        gsum[2] * invS * ((float)r2 * invS));
  }
  int cb0 = scb[0], cb1 = scb[1], cb2 = scb[2];
  if (cb0 <= CAP - 256 && cb1 <= CAP - 256 && cb2 <= CAP - 256) return;
  int t = blockIdx.x * 256 + tid;
  int e = idx[t];
  float gv = gval[t];
  int lane = tid & 63, w = tid >> 6;
  unsigned long long m0 = __ballot(e == 0);
  unsigned long long m1 = __ballot(e == 1);
  unsigned long long m2 = __ballot(e == 2);
  if (lane == 0) {
    whist[w][0] = __popcll(m0);
    whist[w][1] = __popcll(m1);
    whist[w][2] = __popcll(m2);
  }
  __syncthreads();
  int pre = 0;
  for (int ww = 0; ww < 3; ++ww)
    if (ww < w) pre += whist[ww][e];
  unsigned long long lt = (1ull << lane) - 1ull;
  unsigned long long me = (e == 0) ? m0 : (e == 1) ? m1 : m2;
  int cb = (e == 0) ? cb0 : (e == 1) ? cb1 : cb2;
  int pos = cb + pre + __popcll(me & lt);
  bool dropf = (pos >= CAP);
  unsigned long long db = __ballot(dropf);
  if (db) {
    int base = 0;
    if (lane == 0) base = atomicAdd(ndrop, __popcll(db));
    base = __shfl(base, 0);
    if (dropf) {
      int rank = __popcll(db & lt);
      int b = t / LNTOK;
      drop[base + rank] = t | (e << 20);
      atomicAdd(&gbe[b * 3 + e], -gv);
    }
  }
}

// ---------------------------------------------------------------------------
// K3b: z[b,e,:] -= g*x[t] for each dropped token; load-balanced over grid.
__global__ __launch_bounds__(256) void k3b_sub(const float* __restrict__ x,
                                               const float* __restrict__ gval,
                                               const int* __restrict__ drop,
                                               const int* __restrict__ ndrop,
                                               float* __restrict__ z) {
  int nd = *ndrop;
  for (int i = blockIdx.x; i < nd; i += gridDim.x) {
    int ent = drop[i];
    int t = ent & 0xFFFFF;
    int e = ent >> 20;
    int b = t / LNTOK;
    int r = t % LNTOK;
    int n = r / LL, l = r % LL;
    float g = gval[t];
    const float* row = x + (size_t)((b * LL + l) * NN + n) * DD;
    float* zr = z + (size_t)b * 3072 + e * 1024;
    int d = threadIdx.x * 4;
    float4 v = *(const float4*)(row + d);
    atomicAdd(&zr[d + 0], -g * v.x);
    atomicAdd(&zr[d + 1], -g * v.y);
    atomicAdd(&zr[d + 2], -g * v.z);
    atomicAdd(&zr[d + 3], -g * v.w);
  }
}

// ---------------------------------------------------------------------------
// K4: ys += z[16,3072] @ We[3072,1024]. grid 384 = 8 n-tiles(128) x 48 k-chunks(64).
__global__ __launch_bounds__(256) void k4_we(const float* __restrict__ z,
                                             const float* __restrict__ We,
                                             float* __restrict__ ys) {
  __shared__ float zt[16][64];     // 4 KB
  __shared__ float Ct[16][128];    // 8 KB
  int tid = threadIdx.x;
  int nt = blockIdx.x & 7, ks = blockIdx.x >> 3;
  int n0 = nt * 128, k0 = ks * 64;
  for (int i = tid; i < 1024; i += 256)
    zt[i >> 6][i & 63] = z[(i >> 6) * 3072 + k0 + (i & 63)];
  for (int i = tid; i < 2048; i += 256) ((float*)Ct)[i] = 0.f;
  __syncthreads();
  int c4 = (tid & 31) * 4;
  int kg = tid >> 5;               // 8 k-groups x 8 k
  float4 acc[16];
#pragma unroll
  for (int m = 0; m < 16; ++m) acc[m] = make_float4(0.f, 0.f, 0.f, 0.f);
  const float* wp = We + (size_t)(k0 + kg * 8) * 1024 + n0 + c4;
#pragma unroll
  for (int kk = 0; kk < 8; ++kk) {
    float4 bv = *(const float4*)(wp + (size_t)kk * 1024);
#pragma unroll
    for (int m = 0; m < 16; ++m) {
      float a = zt[m][kg * 8 + kk];
      acc[m].x += a * bv.x; acc[m].y += a * bv.y;
      acc[m].z += a * bv.z; acc[m].w += a * bv.w;
    }
  }
#pragma unroll
  for (int m = 0; m < 16; ++m) {
    atomicAdd(&Ct[m][c4 + 0], acc[m].x);
    atomicAdd(&Ct[m][c4 + 1], acc[m].y);
    atomicAdd(&Ct[m][c4 + 2], acc[m].z);
    atomicAdd(&Ct[m][c4 + 3], acc[m].w);
  }
  __syncthreads();
  for (int i = tid; i < 2048; i += 256) {
    int m = i >> 7;
    int h = ((i & 127) + ks * 8) & 127;   // stagger across k-splits
    atomicAdd(&ys[m * 1024 + n0 + h], Ct[m][h]);
  }
}

// ---------------------------------------------------------------------------
// K5: out = ((ys + gbe.be)[16,1024] @ Wp[1024,4096] + 1536*bp)/cnt.
// grid 256 = 32 h-tiles(128) x 8 k-chunks(128). out pre-zeroed.
__global__ __launch_bounds__(256) void k5_out(const float* __restrict__ ys,
                                              const float* __restrict__ Wp,
                                              const float* __restrict__ be,
                                              const float* __restrict__ gbe,
                                              const float* __restrict__ bp,
                                              const int* __restrict__ cnti,
                                              float* __restrict__ out) {
  __shared__ float yt[16][128];
  __shared__ float Ct[16][128];
  __shared__ float sgbe[48];
  __shared__ float sinv[16];
  int tid = threadIdx.x;
  int ht = blockIdx.x & 31, ks = blockIdx.x >> 5;
  int n0 = ht * 128, k0 = ks * 128;
  if (tid < 48) sgbe[tid] = gbe[tid];
  if (tid < 16) sinv[tid] = 1.0f / fmaxf(1.0f, (float)cnti[tid]);
  for (int i = tid; i < 2048; i += 256) ((float*)Ct)[i] = 0.f;
  __syncthreads();
  for (int i = tid; i < 2048; i += 256) {
    int m = i >> 7, kk = i & 127;
    int k = k0 + kk;
    yt[m][kk] = ys[m * 1024 + k] + sgbe[m * 3 + 0] * be[k] +
                sgbe[m * 3 + 1] * be[1024 + k] + sgbe[m * 3 + 2] * be[2048 + k];
  }
  __syncthreads();
  int c4 = (tid & 31) * 4;
  int kg = tid >> 5;               // 8 k-groups x 16 k
  float4 acc[16];
#pragma unroll
  for (int m = 0; m < 16; ++m) acc[m] = make_float4(0.f, 0.f, 0.f, 0.f);
  const float* wpp = Wp + (size_t)(k0 + kg * 16) * HH + n0 + c4;
#pragma unroll
  for (int kk = 0; kk < 16; ++kk) {
    float4 bv = *(const float4*)(wpp + (size_t)kk * HH);
#pragma unroll
    for (int m = 0; m < 16; ++m) {
      float a = yt[m][kg * 16 + kk];
      acc[m].x += a * bv.x; acc[m].y += a * bv.y;
      acc[m].z += a * bv.z; acc[m].w += a * bv.w;
    }
  }
#pragma unroll
  for (int m = 0; m < 16; ++m) {
    atomicAdd(&Ct[m][c4 + 0], acc[m].x);
    atomicAdd(&Ct[m][c4 + 1], acc[m].y);
    atomicAdd(&Ct[m][c4 + 2], acc[m].z);
    atomicAdd(&Ct[m][c4 + 3], acc[m].w);
  }
  __syncthreads();
  for (int i = tid; i < 2048; i += 256) {
    int m = i >> 7;
    int h = ((i & 127) + ks * 16) & 127;  // stagger across k-splits
    float v = Ct[m][h];
    if (ks == 0) v += 1536.0f * bp[n0 + h];
    atomicAdd(&out[(size_t)m * HH + n0 + h], v * sinv[m]);
  }
}

// ---------------------------------------------------------------------------
extern "C" void kernel_launch(void* const* d_in, const int* in_sizes, int n_in,
                              void* d_out, int out_size, void* d_ws, size_t ws_size,
                              hipStream_t stream) {
  const float* x    = (const float*)d_in[0];
  const void*  mask = d_in[1];
  const float* wg   = (const float*)d_in[2];
  const float* We   = (const float*)d_in[3];
  const float* be   = (const float*)d_in[4];
  const float* Wp   = (const float*)d_in[5];
  const float* bp   = (const float*)d_in[6];
  float* out = (float*)d_out;
  float* wsf = (float*)d_ws;
  int*   wsi = (int*)d_ws;

  // zero atomic targets + z + ys (ws/out are not re-poisoned between replays)
  hipMemsetAsync(d_ws, 0, (size_t)OFF_ZEROEND * 4, stream);
  hipMemsetAsync(d_out, 0, (size_t)out_size * 4, stream);

  k0_mask<<<96, 256, 0, stream>>>(mask, wsi + OFF_CNTI);
  k1_fused<<<768, 256, 0, stream>>>(x, wg, wsi + OFF_IDX, wsf + OFF_GVAL,
                                    wsi + OFF_HIST, wsf + OFF_GSUM,
                                    wsf + OFF_GBE, wsf + OFF_Z);
  k3a_drops<<<96, 256, 0, stream>>>(wsi + OFF_IDX, wsf + OFF_GVAL,
                                    wsi + OFF_HIST, wsf + OFF_GSUM,
                                    wsf + OFF_GBE, wsi + OFF_DROP,
                                    wsi + OFF_NDROP, out + 65536);
  k3b_sub<<<128, 256, 0, stream>>>(x, wsf + OFF_GVAL, wsi + OFF_DROP,
                                   wsi + OFF_NDROP, wsf + OFF_Z);
  k4_we<<<384, 256, 0, stream>>>(wsf + OFF_Z, We, wsf + OFF_YS);
  k5_out<<<256, 256, 0, stream>>>(wsf + OFF_YS, Wp, be, wsf + OFF_GBE, bp,
                                  wsi + OFF_CNTI, out);
}

// Round 5
// 195.425 us; speedup vs baseline: 1.2297x; 1.0064x over previous
//
#include <hip/hip_runtime.h>
#include <hip/hip_bf16.h>
#include <cstdint>

// Problem constants
#define LL 3
#define NN 512
#define DD 1024
#define HH 4096
#define SS 24576    // B*N*L tokens
#define LNTOK 1536  // L*N tokens per batch
#define CAP 8192    // ceil(S/E)

// ws offsets in 4-byte words (528 KB total, proven available in rounds 3/4)
#define OFF_HIST    0       // int[96*3] pad 640
#define OFF_GSUM    640     // float[3] pad 64
#define OFF_GBE     704     // float[16*3] pad 64
#define OFF_CNTI    768     // int[16] pad 64
#define OFF_NDROP   832     // int[1] pad 128
#define OFF_Z       960     // float[16*3*1024]
#define OFF_YS      50112   // float[16*1024]
#define OFF_ZEROEND 66496   // everything below here is zeroed each call
#define OFF_IDX     66496   // int[S]
#define OFF_GVAL    91072   // float[S]
#define OFF_DROP    115648  // int[16384]
#define OFF_END     132032

// ---------------------------------------------------------------------------
// K0: mask zero-count per batch (ballot). grid 96 x 256.
__global__ __launch_bounds__(256) void k0_mask(const void* __restrict__ maskp,
                                               int* __restrict__ cnti) {
  __shared__ int det;
  __shared__ int scnt;
  int tid = threadIdx.x;
  if (tid == 0) { det = 0; scnt = 0; }
  __syncthreads();
  const uint32_t* mw = (const uint32_t*)maskp;
  for (int i = tid; i < LNTOK; i += 256) {   // sniff encoding
    uint32_t v = mw[i];
    if (v == 0x3F800000u) det = 2;   // float32 0/1
    else if (v > 1u) det = 1;        // packed bool bytes
  }
  __syncthreads();
  int t = blockIdx.x * 256 + tid;
  int zero;
  if (det == 1) zero = (((const uint8_t*)maskp)[t] == 0);
  else          zero = (mw[t] == 0);
  unsigned long long bal = __ballot(zero);
  if ((tid & 63) == 0) atomicAdd(&scnt, __popcll(bal));
  __syncthreads();
  if (tid == 0) atomicAdd(&cnti[blockIdx.x / 6], scnt);  // 6 blocks per batch
}

// ---------------------------------------------------------------------------
// K1: gating ONLY (no z work, no bulk atomics). grid 1536 x 256.
// Block = 16 tokens (uniform b, uniform 256-chunk). Wave = 4 tokens.
__global__ __launch_bounds__(256, 6) void k1_gate(const float* __restrict__ x,
                                                  const float* __restrict__ wg,
                                                  int* __restrict__ idx,
                                                  float* __restrict__ gval,
                                                  int* __restrict__ hist,
                                                  float* __restrict__ gsum,
                                                  float* __restrict__ gbe) {
  __shared__ float wgT[3][1024];       // 12 KB
  __shared__ float part[16 * 195];     // [tok][e][65 padded] = 12.5 KB
  __shared__ float sd[48];
  __shared__ float sG[3], sB[3];
  __shared__ int   sH[3];
  int tid = threadIdx.x, lane = tid & 63, w = tid >> 6;
  for (int i = tid; i < 3072; i += 256) wgT[i % 3][i / 3] = wg[i];
  if (tid < 3) { sG[tid] = 0.f; sB[tid] = 0.f; sH[tid] = 0; }
  __syncthreads();
  int t0 = blockIdx.x * 16;
  int b = t0 / LNTOK;          // uniform: 16 | 1536
  int r0 = t0 % LNTOK;

  // ---- Phase A: partial dots -> LDS ----
#pragma unroll
  for (int k = 0; k < 4; ++k) {
    int tok = w * 4 + k;
    int r = r0 + tok;
    int n = r / LL, l = r % LL;
    const float* row = x + (size_t)((b * LL + l) * NN + n) * DD + lane * 4;
    float4 v0 = *(const float4*)(row);
    float4 v1 = *(const float4*)(row + 256);
    float4 v2 = *(const float4*)(row + 512);
    float4 v3 = *(const float4*)(row + 768);
    int dd = lane * 4;
    const float4 w00 = *(const float4*)(&wgT[0][dd]);
    const float4 w01 = *(const float4*)(&wgT[0][dd + 256]);
    const float4 w02 = *(const float4*)(&wgT[0][dd + 512]);
    const float4 w03 = *(const float4*)(&wgT[0][dd + 768]);
    float d0 = v0.x * w00.x + v0.y * w00.y + v0.z * w00.z + v0.w * w00.w +
               v1.x * w01.x + v1.y * w01.y + v1.z * w01.z + v1.w * w01.w +
               v2.x * w02.x + v2.y * w02.y + v2.z * w02.z + v2.w * w02.w +
               v3.x * w03.x + v3.y * w03.y + v3.z * w03.z + v3.w * w03.w;
    const float4 w10 = *(const float4*)(&wgT[1][dd]);
    const float4 w11 = *(const float4*)(&wgT[1][dd + 256]);
    const float4 w12 = *(const float4*)(&wgT[1][dd + 512]);
    const float4 w13 = *(const float4*)(&wgT[1][dd + 768]);
    float d1 = v0.x * w10.x + v0.y * w10.y + v0.z * w10.z + v0.w * w10.w +
               v1.x * w11.x + v1.y * w11.y + v1.z * w11.z + v1.w * w11.w +
               v2.x * w12.x + v2.y * w12.y + v2.z * w12.z + v2.w * w12.w +
               v3.x * w13.x + v3.y * w13.y + v3.z * w13.z + v3.w * w13.w;
    const float4 w20 = *(const float4*)(&wgT[2][dd]);
    const float4 w21 = *(const float4*)(&wgT[2][dd + 256]);
    const float4 w22 = *(const float4*)(&wgT[2][dd + 512]);
    const float4 w23 = *(const float4*)(&wgT[2][dd + 768]);
    float d2 = v0.x * w20.x + v0.y * w20.y + v0.z * w20.z + v0.w * w20.w +
               v1.x * w21.x + v1.y * w21.y + v1.z * w21.z + v1.w * w21.w +
               v2.x * w22.x + v2.y * w22.y + v2.z * w22.z + v2.w * w22.w +
               v3.x * w23.x + v3.y * w23.y + v3.z * w23.z + v3.w * w23.w;
    part[tok * 195 + lane] = d0;
    part[tok * 195 + 65 + lane] = d1;
    part[tok * 195 + 130 + lane] = d2;
  }
  __syncthreads();

  // ---- Phase B: 48 parallel 64-way sums (conflict-free: stride 65) ----
  if (tid < 48) {
    const float* p = part + tid * 65;
    float s0 = 0, s1 = 0, s2 = 0, s3 = 0;
#pragma unroll
    for (int l = 0; l < 64; l += 4) {
      s0 += p[l]; s1 += p[l + 1]; s2 += p[l + 2]; s3 += p[l + 3];
    }
    sd[tid] = (s0 + s1) + (s2 + s3);
  }
  __syncthreads();

  // ---- Phase B2: softmax/argmax for 16 tokens ----
  if (tid < 16) {
    float d0 = sd[tid * 3], d1 = sd[tid * 3 + 1], d2 = sd[tid * 3 + 2];
    float m = d0; int id = 0;
    if (d1 > m) { m = d1; id = 1; }
    if (d2 > m) { m = d2; id = 2; }
    float e0 = expf(d0 - m), e1 = expf(d1 - m), e2 = expf(d2 - m);
    float inv = 1.0f / (e0 + e1 + e2);   // gate prob of argmax expert
    int t = t0 + tid;
    idx[t] = id;
    gval[t] = inv;
    atomicAdd(&sG[0], e0 * inv);
    atomicAdd(&sG[1], e1 * inv);
    atomicAdd(&sG[2], e2 * inv);
    atomicAdd(&sB[id], inv);
    atomicAdd(&sH[id], 1);
  }
  __syncthreads();
  if (tid < 3) {
    atomicAdd(&gsum[tid], sG[tid]);
    atomicAdd(&gbe[b * 3 + tid], sB[tid]);
    atomicAdd(&hist[(blockIdx.x >> 4) * 3 + tid], sH[tid]);
  }
}

// ---------------------------------------------------------------------------
// K2: z accumulation, ownership-partitioned (register accumulators).
// grid 1024 = 16 b x 16 slices(64 floats) x 4 token-quarters(384).
// x re-read hits L3 (proven by replay FETCH). Only 192 atomics/block, 4-way.
__global__ __launch_bounds__(256, 4) void k2_zacc(const float* __restrict__ x,
                                                  const int* __restrict__ idx,
                                                  const float* __restrict__ gval,
                                                  float* __restrict__ z) {
  __shared__ float sg[384];
  __shared__ int   se[384];
  __shared__ float pacc[4][3][64];
  int tid = threadIdx.x;
  int blk = blockIdx.x;
  int b = blk >> 6, s = (blk >> 2) & 15, q = blk & 3;
  int tg = tid >> 6, ld = tid & 63;
  for (int i = tid; i < 384; i += 256) {
    int t = b * LNTOK + q * 384 + i;
    sg[i] = gval[t];
    se[i] = idx[t];
  }
  __syncthreads();
  float a0 = 0.f, a1 = 0.f, a2 = 0.f;
  int n0 = q * 128 + tg * 32;
  const float* xb = x + (size_t)b * LL * NN * DD + s * 64 + ld;
  int sb = tg * 96;
#pragma unroll 4
  for (int j = 0; j < 32; ++j) {
    int n = n0 + j;
#pragma unroll
    for (int l = 0; l < 3; ++l) {
      float v = xb[(size_t)(l * NN + n) * DD];
      int si = sb + j * 3 + l;
      float g = sg[si];
      int e = se[si];
      a0 += (e == 0) ? g * v : 0.f;
      a1 += (e == 1) ? g * v : 0.f;
      a2 += (e == 2) ? g * v : 0.f;
    }
  }
  pacc[tg][0][ld] = a0;
  pacc[tg][1][ld] = a1;
  pacc[tg][2][ld] = a2;
  __syncthreads();
  if (tid < 192) {
    int e = tid / 64, d = tid & 63;
    float ssum = (pacc[0][e][d] + pacc[1][e][d]) + (pacc[2][e][d] + pacc[3][e][d]);
    atomicAdd(&z[(size_t)b * 3072 + e * 1024 + s * 64 + d], ssum);
  }
}

// ---------------------------------------------------------------------------
// K3a: per-chunk prefix from hist, dropped tokens -> compact list, fix gbe;
// block 95 emits l_aux. grid 96 x 256.
__global__ __launch_bounds__(256) void k3a_drops(const int* __restrict__ idx,
                                                 const float* __restrict__ gval,
                                                 const int* __restrict__ hist,
                                                 const float* __restrict__ gsum,
                                                 float* __restrict__ gbe,
                                                 int* __restrict__ drop,
                                                 int* __restrict__ ndrop,
                                                 float* __restrict__ laux_out) {
  __shared__ int sh[288];
  __shared__ int scb[3];
  __shared__ int whist[4][3];
  int tid = threadIdx.x;
  for (int i = tid; i < 288; i += 256) sh[i] = hist[i];
  __syncthreads();
  if (tid < 3) {
    int s = 0;
    for (int c = 0; c < (int)blockIdx.x; ++c) s += sh[c * 3 + tid];
    scb[tid] = s;
  }
  __syncthreads();
  if (blockIdx.x == 95 && tid == 0) {
    int r0 = scb[0] + sh[285], r1 = scb[1] + sh[286], r2 = scb[2] + sh[287];
    float invS = 1.0f / (float)SS;
    *laux_out = 3.0f * (gsum[0] * invS * ((float)r0 * invS) +
                        gsum[1] * invS * ((float)r1 * invS) +
                        gsum[2] * invS * ((float)r2 * invS));
  }
  int cb0 = scb[0], cb1 = scb[1], cb2 = scb[2];
  if (cb0 <= CAP - 256 && cb1 <= CAP - 256 && cb2 <= CAP - 256) return;
  int t = blockIdx.x * 256 + tid;
  int e = idx[t];
  float gv = gval[t];
  int lane = tid & 63, w = tid >> 6;
  unsigned long long m0 = __ballot(e == 0);
  unsigned long long m1 = __ballot(e == 1);
  unsigned long long m2 = __ballot(e == 2);
  if (lane == 0) {
    whist[w][0] = __popcll(m0);
    whist[w][1] = __popcll(m1);
    whist[w][2] = __popcll(m2);
  }
  __syncthreads();
  int pre = 0;
  for (int ww = 0; ww < 3; ++ww)
    if (ww < w) pre += whist[ww][e];
  unsigned long long lt = (1ull << lane) - 1ull;
  unsigned long long me = (e == 0) ? m0 : (e == 1) ? m1 : m2;
  int cb = (e == 0) ? cb0 : (e == 1) ? cb1 : cb2;
  int pos = cb + pre + __popcll(me & lt);
  bool dropf = (pos >= CAP);
  unsigned long long db = __ballot(dropf);
  if (db) {
    int base = 0;
    if (lane == 0) base = atomicAdd(ndrop, __popcll(db));
    base = __shfl(base, 0);
    if (dropf) {
      int rank = __popcll(db & lt);
      int b = t / LNTOK;
      drop[base + rank] = t | (e << 20);
      atomicAdd(&gbe[b * 3 + e], -gv);
    }
  }
}

// ---------------------------------------------------------------------------
// K3b: z[b,e,:] -= g*x[t] for each dropped token (few hundred expected).
__global__ __launch_bounds__(256) void k3b_sub(const float* __restrict__ x,
                                               const float* __restrict__ gval,
                                               const int* __restrict__ drop,
                                               const int* __restrict__ ndrop,
                                               float* __restrict__ z) {
  int nd = *ndrop;
  for (int i = blockIdx.x; i < nd; i += gridDim.x) {
    int ent = drop[i];
    int t = ent & 0xFFFFF;
    int e = ent >> 20;
    int b = t / LNTOK;
    int r = t % LNTOK;
    int n = r / LL, l = r % LL;
    float g = gval[t];
    const float* row = x + (size_t)((b * LL + l) * NN + n) * DD;
    float* zr = z + (size_t)b * 3072 + e * 1024;
    int d = threadIdx.x * 4;
    float4 v = *(const float4*)(row + d);
    atomicAdd(&zr[d + 0], -g * v.x);
    atomicAdd(&zr[d + 1], -g * v.y);
    atomicAdd(&zr[d + 2], -g * v.z);
    atomicAdd(&zr[d + 3], -g * v.w);
  }
}

// ---------------------------------------------------------------------------
// K4: ys += z[16,3072] @ We[3072,1024]. grid 384 = 8 n-tiles(128) x 48 k-chunks(64).
__global__ __launch_bounds__(256) void k4_we(const float* __restrict__ z,
                                             const float* __restrict__ We,
                                             float* __restrict__ ys) {
  __shared__ float zt[16][64];     // 4 KB
  __shared__ float Ct[16][128];    // 8 KB
  int tid = threadIdx.x;
  int nt = blockIdx.x & 7, ks = blockIdx.x >> 3;
  int n0 = nt * 128, k0 = ks * 64;
  for (int i = tid; i < 1024; i += 256)
    zt[i >> 6][i & 63] = z[(i >> 6) * 3072 + k0 + (i & 63)];
  for (int i = tid; i < 2048; i += 256) ((float*)Ct)[i] = 0.f;
  __syncthreads();
  int c4 = (tid & 31) * 4;
  int kg = tid >> 5;               // 8 k-groups x 8 k
  float4 acc[16];
#pragma unroll
  for (int m = 0; m < 16; ++m) acc[m] = make_float4(0.f, 0.f, 0.f, 0.f);
  const float* wp = We + (size_t)(k0 + kg * 8) * 1024 + n0 + c4;
#pragma unroll
  for (int kk = 0; kk < 8; ++kk) {
    float4 bv = *(const float4*)(wp + (size_t)kk * 1024);
#pragma unroll
    for (int m = 0; m < 16; ++m) {
      float a = zt[m][kg * 8 + kk];
      acc[m].x += a * bv.x; acc[m].y += a * bv.y;
      acc[m].z += a * bv.z; acc[m].w += a * bv.w;
    }
  }
#pragma unroll
  for (int m = 0; m < 16; ++m) {
    atomicAdd(&Ct[m][c4 + 0], acc[m].x);
    atomicAdd(&Ct[m][c4 + 1], acc[m].y);
    atomicAdd(&Ct[m][c4 + 2], acc[m].z);
    atomicAdd(&Ct[m][c4 + 3], acc[m].w);
  }
  __syncthreads();
  for (int i = tid; i < 2048; i += 256) {
    int m = i >> 7;
    int h = ((i & 127) + ks * 8) & 127;   // stagger across k-splits
    atomicAdd(&ys[m * 1024 + n0 + h], Ct[m][h]);
  }
}

// ---------------------------------------------------------------------------
// K5: out[b, h-tile] = ((ys + gbe.be) @ Wp + 1536*bp)/cnt, non-atomic.
// grid 64 (each block owns a 64-wide h-tile, full K=1024).
__global__ __launch_bounds__(256) void k5_out(const float* __restrict__ ys,
                                              const float* __restrict__ Wp,
                                              const float* __restrict__ be,
                                              const float* __restrict__ gbe,
                                              const float* __restrict__ bp,
                                              const int* __restrict__ cnti,
                                              float* __restrict__ out) {
  __shared__ float ytT[1024][16];   // 64 KB, transposed (k-major)
  __shared__ float Ct[16][64];
  __shared__ float sgbe[48];
  __shared__ float sinv[16];
  int tid = threadIdx.x;
  int n0 = blockIdx.x * 64;
  if (tid < 48) sgbe[tid] = gbe[tid];
  if (tid < 16) sinv[tid] = 1.0f / fmaxf(1.0f, (float)cnti[tid]);
  for (int i = tid; i < 1024; i += 256) ((float*)Ct)[i] = 0.f;
  __syncthreads();
  for (int i = tid; i < 16384; i += 256) {
    int m = i >> 10, k = i & 1023;
    ytT[k][m] = ys[m * 1024 + k] + sgbe[m * 3 + 0] * be[k] +
                sgbe[m * 3 + 1] * be[1024 + k] + sgbe[m * 3 + 2] * be[2048 + k];
  }
  __syncthreads();
  int kg = tid >> 4, nl = tid & 15;   // 16 kg x 16 nl (4 h each)
  int h0 = nl * 4;
  float4 acc[16];
#pragma unroll
  for (int m = 0; m < 16; ++m) acc[m] = make_float4(0.f, 0.f, 0.f, 0.f);
  const float* wpp = Wp + (size_t)(kg * 64) * HH + n0 + h0;
  for (int kk = 0; kk < 64; ++kk) {
    int k = kg * 64 + kk;
    float4 bv = *(const float4*)(wpp + (size_t)kk * HH);
    const float4 y0 = *(const float4*)(&ytT[k][0]);
    const float4 y1 = *(const float4*)(&ytT[k][4]);
    const float4 y2 = *(const float4*)(&ytT[k][8]);
    const float4 y3 = *(const float4*)(&ytT[k][12]);
    acc[0].x += y0.x * bv.x;  acc[0].y += y0.x * bv.y;  acc[0].z += y0.x * bv.z;  acc[0].w += y0.x * bv.w;
    acc[1].x += y0.y * bv.x;  acc[1].y += y0.y * bv.y;  acc[1].z += y0.y * bv.z;  acc[1].w += y0.y * bv.w;
    acc[2].x += y0.z * bv.x;  acc[2].y += y0.z * bv.y;  acc[2].z += y0.z * bv.z;  acc[2].w += y0.z * bv.w;
    acc[3].x += y0.w * bv.x;  acc[3].y += y0.w * bv.y;  acc[3].z += y0.w * bv.z;  acc[3].w += y0.w * bv.w;
    acc[4].x += y1.x * bv.x;  acc[4].y += y1.x * bv.y;  acc[4].z += y1.x * bv.z;  acc[4].w += y1.x * bv.w;
    acc[5].x += y1.y * bv.x;  acc[5].y += y1.y * bv.y;  acc[5].z += y1.y * bv.z;  acc[5].w += y1.y * bv.w;
    acc[6].x += y1.z * bv.x;  acc[6].y += y1.z * bv.y;  acc[6].z += y1.z * bv.z;  acc[6].w += y1.z * bv.w;
    acc[7].x += y1.w * bv.x;  acc[7].y += y1.w * bv.y;  acc[7].z += y1.w * bv.z;  acc[7].w += y1.w * bv.w;
    acc[8].x += y2.x * bv.x;  acc[8].y += y2.x * bv.y;  acc[8].z += y2.x * bv.z;  acc[8].w += y2.x * bv.w;
    acc[9].x += y2.y * bv.x;  acc[9].y += y2.y * bv.y;  acc[9].z += y2.y * bv.z;  acc[9].w += y2.y * bv.w;
    acc[10].x += y2.z * bv.x; acc[10].y += y2.z * bv.y; acc[10].z += y2.z * bv.z; acc[10].w += y2.z * bv.w;
    acc[11].x += y2.w * bv.x; acc[11].y += y2.w * bv.y; acc[11].z += y2.w * bv.z; acc[11].w += y2.w * bv.w;
    acc[12].x += y3.x * bv.x; acc[12].y += y3.x * bv.y; acc[12].z += y3.x * bv.z; acc[12].w += y3.x * bv.w;
    acc[13].x += y3.y * bv.x; acc[13].y += y3.y * bv.y; acc[13].z += y3.y * bv.z; acc[13].w += y3.y * bv.w;
    acc[14].x += y3.z * bv.x; acc[14].y += y3.z * bv.y; acc[14].z += y3.z * bv.z; acc[14].w += y3.z * bv.w;
    acc[15].x += y3.w * bv.x; acc[15].y += y3.w * bv.y; acc[15].z += y3.w * bv.z; acc[15].w += y3.w * bv.w;
  }
#pragma unroll
  for (int m = 0; m < 16; ++m) {
    atomicAdd(&Ct[m][h0 + 0], acc[m].x);
    atomicAdd(&Ct[m][h0 + 1], acc[m].y);
    atomicAdd(&Ct[m][h0 + 2], acc[m].z);
    atomicAdd(&Ct[m][h0 + 3], acc[m].w);
  }
  __syncthreads();
  for (int i = tid; i < 1024; i += 256) {
    int m = i >> 6, h = i & 63;
    out[(size_t)m * HH + n0 + h] = (Ct[m][h] + 1536.0f * bp[n0 + h]) * sinv[m];
  }
}

// ---------------------------------------------------------------------------
extern "C" void kernel_launch(void* const* d_in, const int* in_sizes, int n_in,
                              void* d_out, int out_size, void* d_ws, size_t ws_size,
                              hipStream_t stream) {
  const float* x    = (const float*)d_in[0];
  const void*  mask = d_in[1];
  const float* wg   = (const float*)d_in[2];
  const float* We   = (const float*)d_in[3];
  const float* be   = (const float*)d_in[4];
  const float* Wp   = (const float*)d_in[5];
  const float* bp   = (const float*)d_in[6];
  float* out = (float*)d_out;
  float* wsf = (float*)d_ws;
  int*   wsi = (int*)d_ws;

  // zero scalar targets + z + ys (ws is not re-poisoned between replays)
  hipMemsetAsync(d_ws, 0, (size_t)OFF_ZEROEND * 4, stream);

  k0_mask<<<96, 256, 0, stream>>>(mask, wsi + OFF_CNTI);
  k1_gate<<<1536, 256, 0, stream>>>(x, wg, wsi + OFF_IDX, wsf + OFF_GVAL,
                                    wsi + OFF_HIST, wsf + OFF_GSUM,
                                    wsf + OFF_GBE);
  k2_zacc<<<1024, 256, 0, stream>>>(x, wsi + OFF_IDX, wsf + OFF_GVAL,
                                    wsf + OFF_Z);
  k3a_drops<<<96, 256, 0, stream>>>(wsi + OFF_IDX, wsf + OFF_GVAL,
                                    wsi + OFF_HIST, wsf + OFF_GSUM,
                                    wsf + OFF_GBE, wsi + OFF_DROP,
                                    wsi + OFF_NDROP, out + 65536);
  k3b_sub<<<128, 256, 0, stream>>>(x, wsf + OFF_GVAL, wsi + OFF_DROP,
                                   wsi + OFF_NDROP, wsf + OFF_Z);
  k4_we<<<384, 256, 0, stream>>>(wsf + OFF_Z, We, wsf + OFF_YS);
  k5_out<<<64, 256, 0, stream>>>(wsf + OFF_YS, Wp, be, wsf + OFF_GBE, bp,
                                 wsi + OFF_CNTI, out);
}

// Round 6
// 108.295 us; speedup vs baseline: 2.2191x; 1.8046x over previous
//
#include <hip/hip_runtime.h>
#include <hip/hip_bf16.h>
#include <cstdint>

// Problem constants
#define LL 3
#define NN 512
#define DD 1024
#define HH 4096
#define SS 24576    // B*N*L tokens
#define LNTOK 1536  // L*N tokens per batch
#define CAP 8192    // ceil(S/E)

// ws offsets in 4-byte words
#define OFF_HIST    0       // int[96*3] pad 640
#define OFF_GSUM    640     // float[3] pad 64
#define OFF_GBE     704     // float[16*3] pad 64
#define OFF_CNTI    768     // int[16] pad 64
#define OFF_NDROP   832     // int[1] pad 128
#define OFF_Z       960     // float[16*3*1024]
#define OFF_YS      50112   // float[16*1024] (fallback path only)
#define OFF_ZEROEND 66496   // region [0, here) zeroed each call
#define OFF_IDX     66496   // int[S]
#define OFF_GVAL    91072   // float[S]
#define OFF_DROP    115648  // int[16384]
#define OFF_END     132032  // = 528 KB, proven available
// big-ws extension (partials; only used when ws_size >= OFF_BIG_END*4)
#define OFF_PZ      132032  // float[32][16][1024] = 524288
#define OFF_PP      656320  // float[16][16][4096] = 1048576
#define OFF_YS2     1704896 // float[16*1024]
#define OFF_BIG_END 1721280 // 6.6 MB

// ---------------------------------------------------------------------------
// K0: mask zero-count per batch (ballot). grid 96 x 256.
__global__ __launch_bounds__(256) void k0_mask(const void* __restrict__ maskp,
                                               int* __restrict__ cnti) {
  __shared__ int det;
  __shared__ int scnt;
  int tid = threadIdx.x;
  if (tid == 0) { det = 0; scnt = 0; }
  __syncthreads();
  const uint32_t* mw = (const uint32_t*)maskp;
  for (int i = tid; i < LNTOK; i += 256) {   // sniff encoding
    uint32_t v = mw[i];
    if (v == 0x3F800000u) det = 2;   // float32 0/1
    else if (v > 1u) det = 1;        // packed bool bytes
  }
  __syncthreads();
  int t = blockIdx.x * 256 + tid;
  int zero;
  if (det == 1) zero = (((const uint8_t*)maskp)[t] == 0);
  else          zero = (mw[t] == 0);
  unsigned long long bal = __ballot(zero);
  if ((tid & 63) == 0) atomicAdd(&scnt, __popcll(bal));
  __syncthreads();
  if (tid == 0) atomicAdd(&cnti[blockIdx.x / 6], scnt);  // 6 blocks per batch
}

// ---------------------------------------------------------------------------
// K1: gating only. grid 1536 x 256; 16 tokens/block, 4/wave.
// Gate-weight fragments hoisted to registers (lane-dependent only).
__global__ __launch_bounds__(256, 4) void k1_gate(const float* __restrict__ x,
                                                  const float* __restrict__ wg,
                                                  int* __restrict__ idx,
                                                  float* __restrict__ gval,
                                                  int* __restrict__ hist,
                                                  float* __restrict__ gsum,
                                                  float* __restrict__ gbe) {
  __shared__ float wgT[3][1024];       // 12 KB
  __shared__ float part[16 * 195];     // [tok][e][65 padded] = 12.5 KB
  __shared__ float sd[48];
  __shared__ float sG[3], sB[3];
  __shared__ int   sH[3];
  int tid = threadIdx.x, lane = tid & 63, w = tid >> 6;
  for (int i = tid; i < 3072; i += 256) wgT[i % 3][i / 3] = wg[i];
  if (tid < 3) { sG[tid] = 0.f; sB[tid] = 0.f; sH[tid] = 0; }
  __syncthreads();
  int dd = lane * 4;
  float4 W[12];    // 48 VGPR: weight fragments, reused across all tokens
#pragma unroll
  for (int e = 0; e < 3; ++e)
#pragma unroll
    for (int q = 0; q < 4; ++q)
      W[e * 4 + q] = *(const float4*)(&wgT[e][dd + q * 256]);
  int t0 = blockIdx.x * 16;
  int b = t0 / LNTOK;          // uniform: 16 | 1536
  int r0 = t0 % LNTOK;

  // ---- Phase A: partial dots -> LDS ----
#pragma unroll
  for (int k = 0; k < 4; ++k) {
    int tok = w * 4 + k;
    int r = r0 + tok;
    int n = r / LL, l = r % LL;
    const float* row = x + (size_t)((b * LL + l) * NN + n) * DD + dd;
    float4 v0 = *(const float4*)(row);
    float4 v1 = *(const float4*)(row + 256);
    float4 v2 = *(const float4*)(row + 512);
    float4 v3 = *(const float4*)(row + 768);
    float d0 = v0.x * W[0].x + v0.y * W[0].y + v0.z * W[0].z + v0.w * W[0].w +
               v1.x * W[1].x + v1.y * W[1].y + v1.z * W[1].z + v1.w * W[1].w +
               v2.x * W[2].x + v2.y * W[2].y + v2.z * W[2].z + v2.w * W[2].w +
               v3.x * W[3].x + v3.y * W[3].y + v3.z * W[3].z + v3.w * W[3].w;
    float d1 = v0.x * W[4].x + v0.y * W[4].y + v0.z * W[4].z + v0.w * W[4].w +
               v1.x * W[5].x + v1.y * W[5].y + v1.z * W[5].z + v1.w * W[5].w +
               v2.x * W[6].x + v2.y * W[6].y + v2.z * W[6].z + v2.w * W[6].w +
               v3.x * W[7].x + v3.y * W[7].y + v3.z * W[7].z + v3.w * W[7].w;
    float d2 = v0.x * W[8].x + v0.y * W[8].y + v0.z * W[8].z + v0.w * W[8].w +
               v1.x * W[9].x + v1.y * W[9].y + v1.z * W[9].z + v1.w * W[9].w +
               v2.x * W[10].x + v2.y * W[10].y + v2.z * W[10].z + v2.w * W[10].w +
               v3.x * W[11].x + v3.y * W[11].y + v3.z * W[11].z + v3.w * W[11].w;
    part[tok * 195 + lane] = d0;
    part[tok * 195 + 65 + lane] = d1;
    part[tok * 195 + 130 + lane] = d2;
  }
  __syncthreads();

  // ---- Phase B: 48 parallel 64-way sums (bank-spread via stride 65) ----
  if (tid < 48) {
    const float* p = part + tid * 65;
    float s0 = 0, s1 = 0, s2 = 0, s3 = 0;
#pragma unroll
    for (int l = 0; l < 64; l += 4) {
      s0 += p[l]; s1 += p[l + 1]; s2 += p[l + 2]; s3 += p[l + 3];
    }
    sd[tid] = (s0 + s1) + (s2 + s3);
  }
  __syncthreads();

  // ---- Phase B2: softmax/argmax for 16 tokens ----
  if (tid < 16) {
    float d0 = sd[tid * 3], d1 = sd[tid * 3 + 1], d2 = sd[tid * 3 + 2];
    float m = d0; int id = 0;
    if (d1 > m) { m = d1; id = 1; }
    if (d2 > m) { m = d2; id = 2; }
    float e0 = expf(d0 - m), e1 = expf(d1 - m), e2 = expf(d2 - m);
    float inv = 1.0f / (e0 + e1 + e2);   // gate prob of argmax expert
    int t = t0 + tid;
    idx[t] = id;
    gval[t] = inv;
    atomicAdd(&sG[0], e0 * inv);
    atomicAdd(&sG[1], e1 * inv);
    atomicAdd(&sG[2], e2 * inv);
    atomicAdd(&sB[id], inv);
    atomicAdd(&sH[id], 1);
  }
  __syncthreads();
  if (tid < 3) {
    atomicAdd(&gsum[tid], sG[tid]);
    atomicAdd(&gbe[b * 3 + tid], sB[tid]);
    atomicAdd(&hist[(blockIdx.x >> 4) * 3 + tid], sH[tid]);
  }
}

// ---------------------------------------------------------------------------
// K2: z accumulation, ownership-partitioned (register accumulators).
// grid 1024 = 16 b x 16 slices(64 floats) x 4 token-quarters(384).
__global__ __launch_bounds__(256, 4) void k2_zacc(const float* __restrict__ x,
                                                  const int* __restrict__ idx,
                                                  const float* __restrict__ gval,
                                                  float* __restrict__ z) {
  __shared__ float sg[384];
  __shared__ int   se[384];
  __shared__ float pacc[4][3][64];
  int tid = threadIdx.x;
  int blk = blockIdx.x;
  int b = blk >> 6, s = (blk >> 2) & 15, q = blk & 3;
  int tg = tid >> 6, ld = tid & 63;
  for (int i = tid; i < 384; i += 256) {
    int t = b * LNTOK + q * 384 + i;
    sg[i] = gval[t];
    se[i] = idx[t];
  }
  __syncthreads();
  float a0 = 0.f, a1 = 0.f, a2 = 0.f;
  int n0 = q * 128 + tg * 32;
  const float* xb = x + (size_t)b * LL * NN * DD + s * 64 + ld;
  int sb = tg * 96;
#pragma unroll 4
  for (int j = 0; j < 32; ++j) {
    int n = n0 + j;
#pragma unroll
    for (int l = 0; l < 3; ++l) {
      float v = xb[(size_t)(l * NN + n) * DD];
      int si = sb + j * 3 + l;
      float g = sg[si];
      int e = se[si];
      a0 += (e == 0) ? g * v : 0.f;
      a1 += (e == 1) ? g * v : 0.f;
      a2 += (e == 2) ? g * v : 0.f;
    }
  }
  pacc[tg][0][ld] = a0;
  pacc[tg][1][ld] = a1;
  pacc[tg][2][ld] = a2;
  __syncthreads();
  if (tid < 192) {
    int e = tid / 64, d = tid & 63;
    float ssum = (pacc[0][e][d] + pacc[1][e][d]) + (pacc[2][e][d] + pacc[3][e][d]);
    atomicAdd(&z[(size_t)b * 3072 + e * 1024 + s * 64 + d], ssum);
  }
}

// ---------------------------------------------------------------------------
// K3a: per-chunk prefix from hist, dropped tokens -> compact list, fix gbe;
// block 95 emits l_aux. grid 96 x 256.
__global__ __launch_bounds__(256) void k3a_drops(const int* __restrict__ idx,
                                                 const float* __restrict__ gval,
                                                 const int* __restrict__ hist,
                                                 const float* __restrict__ gsum,
                                                 float* __restrict__ gbe,
                                                 int* __restrict__ drop,
                                                 int* __restrict__ ndrop,
                                                 float* __restrict__ laux_out) {
  __shared__ int sh[288];
  __shared__ int scb[3];
  __shared__ int whist[4][3];
  int tid = threadIdx.x;
  for (int i = tid; i < 288; i += 256) sh[i] = hist[i];
  __syncthreads();
  if (tid < 3) {
    int s = 0;
    for (int c = 0; c < (int)blockIdx.x; ++c) s += sh[c * 3 + tid];
    scb[tid] = s;
  }
  __syncthreads();
  if (blockIdx.x == 95 && tid == 0) {
    int r0 = scb[0] + sh[285], r1 = scb[1] + sh[286], r2 = scb[2] + sh[287];
    float invS = 1.0f / (float)SS;
    *laux_out = 3.0f * (gsum[0] * invS * ((float)r0 * invS) +
                        gsum[1] * invS * ((float)r1 * invS) +
                        gsum[2] * invS * ((float)r2 * invS));
  }
  int cb0 = scb[0], cb1 = scb[1], cb2 = scb[2];
  if (cb0 <= CAP - 256 && cb1 <= CAP - 256 && cb2 <= CAP - 256) return;
  int t = blockIdx.x * 256 + tid;
  int e = idx[t];
  float gv = gval[t];
  int lane = tid & 63, w = tid >> 6;
  unsigned long long m0 = __ballot(e == 0);
  unsigned long long m1 = __ballot(e == 1);
  unsigned long long m2 = __ballot(e == 2);
  if (lane == 0) {
    whist[w][0] = __popcll(m0);
    whist[w][1] = __popcll(m1);
    whist[w][2] = __popcll(m2);
  }
  __syncthreads();
  int pre = 0;
  for (int ww = 0; ww < 3; ++ww)
    if (ww < w) pre += whist[ww][e];
  unsigned long long lt = (1ull << lane) - 1ull;
  unsigned long long me = (e == 0) ? m0 : (e == 1) ? m1 : m2;
  int cb = (e == 0) ? cb0 : (e == 1) ? cb1 : cb2;
  int pos = cb + pre + __popcll(me & lt);
  bool dropf = (pos >= CAP);
  unsigned long long db = __ballot(dropf);
  if (db) {
    int base = 0;
    if (lane == 0) base = atomicAdd(ndrop, __popcll(db));
    base = __shfl(base, 0);
    if (dropf) {
      int rank = __popcll(db & lt);
      int b = t / LNTOK;
      drop[base + rank] = t | (e << 20);
      atomicAdd(&gbe[b * 3 + e], -gv);
    }
  }
}

// ---------------------------------------------------------------------------
// K3b: z[b,e,:] -= g*x[t] for each dropped token (few hundred expected).
__global__ __launch_bounds__(256) void k3b_sub(const float* __restrict__ x,
                                               const float* __restrict__ gval,
                                               const int* __restrict__ drop,
                                               const int* __restrict__ ndrop,
                                               float* __restrict__ z) {
  int nd = *ndrop;
  for (int i = blockIdx.x; i < nd; i += gridDim.x) {
    int ent = drop[i];
    int t = ent & 0xFFFFF;
    int e = ent >> 20;
    int b = t / LNTOK;
    int r = t % LNTOK;
    int n = r / LL, l = r % LL;
    float g = gval[t];
    const float* row = x + (size_t)((b * LL + l) * NN + n) * DD;
    float* zr = z + (size_t)b * 3072 + e * 1024;
    int d = threadIdx.x * 4;
    float4 v = *(const float4*)(row + d);
    atomicAdd(&zr[d + 0], -g * v.x);
    atomicAdd(&zr[d + 1], -g * v.y);
    atomicAdd(&zr[d + 2], -g * v.z);
    atomicAdd(&zr[d + 3], -g * v.w);
  }
}

// ---------------------------------------------------------------------------
// K4: PZ[kc] = z-tile @ We-chunk (no atomics). grid 512 = 16 nt(64) x 32 kc(96).
__global__ __launch_bounds__(256) void k4_we(const float* __restrict__ z,
                                             const float* __restrict__ We,
                                             float* __restrict__ pz) {
  __shared__ float ztT[96][20];     // padded/aligned, 7.7 KB
  __shared__ float pacc[4][16][64]; // 16 KB
  int tid = threadIdx.x;
  int nt = blockIdx.x & 15, kc = blockIdx.x >> 4;
  int n0 = nt * 64, k0 = kc * 96;
  for (int i = tid; i < 1536; i += 256) {
    int m = i / 96, kk = i % 96;
    ztT[kk][m] = z[m * 3072 + k0 + kk];
  }
  __syncthreads();
  int kg = tid >> 6, n = tid & 63;
  float acc[16];
#pragma unroll
  for (int m = 0; m < 16; ++m) acc[m] = 0.f;
  const float* wp = We + (size_t)(k0 + kg * 24) * 1024 + n0 + n;
#pragma unroll
  for (int kk = 0; kk < 24; ++kk) {
    float bw = wp[(size_t)kk * 1024];
    int k = kg * 24 + kk;
    const float4 y0 = *(const float4*)(&ztT[k][0]);
    const float4 y1 = *(const float4*)(&ztT[k][4]);
    const float4 y2 = *(const float4*)(&ztT[k][8]);
    const float4 y3 = *(const float4*)(&ztT[k][12]);
    acc[0] += y0.x * bw;  acc[1] += y0.y * bw;  acc[2] += y0.z * bw;  acc[3] += y0.w * bw;
    acc[4] += y1.x * bw;  acc[5] += y1.y * bw;  acc[6] += y1.z * bw;  acc[7] += y1.w * bw;
    acc[8] += y2.x * bw;  acc[9] += y2.y * bw;  acc[10] += y2.z * bw; acc[11] += y2.w * bw;
    acc[12] += y3.x * bw; acc[13] += y3.y * bw; acc[14] += y3.z * bw; acc[15] += y3.w * bw;
  }
#pragma unroll
  for (int m = 0; m < 16; ++m) pacc[kg][m][n] = acc[m];
  __syncthreads();
  for (int i = tid; i < 1024; i += 256) {
    int m = i >> 6, nn = i & 63;
    float s = (pacc[0][m][nn] + pacc[1][m][nn]) + (pacc[2][m][nn] + pacc[3][m][nn]);
    pz[((size_t)kc * 16 + m) * 1024 + n0 + nn] = s;
  }
}

// ---------------------------------------------------------------------------
// K4r: ys2 = sum_kc PZ + gbe.be bias. grid 64 x 256.
__global__ __launch_bounds__(256) void k4r_red(const float* __restrict__ pz,
                                               const float* __restrict__ gbe,
                                               const float* __restrict__ be,
                                               float* __restrict__ ys2) {
  int i = blockIdx.x * 256 + threadIdx.x;  // 16384
  int m = i >> 10, k = i & 1023;
  float s = 0.f;
#pragma unroll 8
  for (int kc = 0; kc < 32; ++kc) s += pz[((size_t)kc * 16 + m) * 1024 + k];
  s += gbe[m * 3 + 0] * be[k] + gbe[m * 3 + 1] * be[1024 + k] +
       gbe[m * 3 + 2] * be[2048 + k];
  ys2[i] = s;
}

// ---------------------------------------------------------------------------
// K5: PP[kc] = ys2-tile @ Wp-chunk (no atomics). grid 1024 = 64 ht(64) x 16 kc(64).
__global__ __launch_bounds__(256) void k5_wp(const float* __restrict__ ys2,
                                             const float* __restrict__ Wp,
                                             float* __restrict__ pp) {
  __shared__ float ytT[64][20];     // 5.1 KB
  __shared__ float pacc[4][16][64]; // 16 KB
  int tid = threadIdx.x;
  int ht = blockIdx.x & 63, kc = blockIdx.x >> 6;
  int h0 = ht * 64, k0 = kc * 64;
  for (int i = tid; i < 1024; i += 256) {
    int m = i >> 6, kk = i & 63;
    ytT[kk][m] = ys2[m * 1024 + k0 + kk];
  }
  __syncthreads();
  int kg = tid >> 6, h = tid & 63;
  float acc[16];
#pragma unroll
  for (int m = 0; m < 16; ++m) acc[m] = 0.f;
  const float* wpp = Wp + (size_t)(k0 + kg * 16) * HH + h0 + h;
#pragma unroll
  for (int kk = 0; kk < 16; ++kk) {
    float bw = wpp[(size_t)kk * HH];
    int k = kg * 16 + kk;
    const float4 y0 = *(const float4*)(&ytT[k][0]);
    const float4 y1 = *(const float4*)(&ytT[k][4]);
    const float4 y2 = *(const float4*)(&ytT[k][8]);
    const float4 y3 = *(const float4*)(&ytT[k][12]);
    acc[0] += y0.x * bw;  acc[1] += y0.y * bw;  acc[2] += y0.z * bw;  acc[3] += y0.w * bw;
    acc[4] += y1.x * bw;  acc[5] += y1.y * bw;  acc[6] += y1.z * bw;  acc[7] += y1.w * bw;
    acc[8] += y2.x * bw;  acc[9] += y2.y * bw;  acc[10] += y2.z * bw; acc[11] += y2.w * bw;
    acc[12] += y3.x * bw; acc[13] += y3.y * bw; acc[14] += y3.z * bw; acc[15] += y3.w * bw;
  }
#pragma unroll
  for (int m = 0; m < 16; ++m) pacc[kg][m][h] = acc[m];
  __syncthreads();
  for (int i = tid; i < 1024; i += 256) {
    int m = i >> 6, hh = i & 63;
    float s = (pacc[0][m][hh] + pacc[1][m][hh]) + (pacc[2][m][hh] + pacc[3][m][hh]);
    pp[((size_t)kc * 16 + m) * HH + h0 + hh] = s;
  }
}

// ---------------------------------------------------------------------------
// K5r: out = (sum_kc PP + 1536*bp) / cnt. grid 256 x 256.
__global__ __launch_bounds__(256) void k5r_red(const float* __restrict__ pp,
                                               const float* __restrict__ bp,
                                               const int* __restrict__ cnti,
                                               float* __restrict__ out) {
  int i = blockIdx.x * 256 + threadIdx.x;  // 65536
  int m = i >> 12, h = i & 4095;
  float s = 0.f;
#pragma unroll 8
  for (int kc = 0; kc < 16; ++kc) s += pp[((size_t)kc * 16 + m) * HH + h];
  float inv = 1.0f / fmaxf(1.0f, (float)cnti[m]);
  out[i] = (s + 1536.0f * bp[h]) * inv;
}

// ---------------------------------------------------------------------------
// Fallback path (small ws): round-5 atomic k4/k5, known-correct.
__global__ __launch_bounds__(256) void k4_we_at(const float* __restrict__ z,
                                                const float* __restrict__ We,
                                                float* __restrict__ ys) {
  __shared__ float zt[16][64];
  __shared__ float Ct[16][128];
  int tid = threadIdx.x;
  int nt = blockIdx.x & 7, ks = blockIdx.x >> 3;
  int n0 = nt * 128, k0 = ks * 64;
  for (int i = tid; i < 1024; i += 256)
    zt[i >> 6][i & 63] = z[(i >> 6) * 3072 + k0 + (i & 63)];
  for (int i = tid; i < 2048; i += 256) ((float*)Ct)[i] = 0.f;
  __syncthreads();
  int c4 = (tid & 31) * 4;
  int kg = tid >> 5;
  float4 acc[16];
#pragma unroll
  for (int m = 0; m < 16; ++m) acc[m] = make_float4(0.f, 0.f, 0.f, 0.f);
  const float* wp = We + (size_t)(k0 + kg * 8) * 1024 + n0 + c4;
#pragma unroll
  for (int kk = 0; kk < 8; ++kk) {
    float4 bv = *(const float4*)(wp + (size_t)kk * 1024);
#pragma unroll
    for (int m = 0; m < 16; ++m) {
      float a = zt[m][kg * 8 + kk];
      acc[m].x += a * bv.x; acc[m].y += a * bv.y;
      acc[m].z += a * bv.z; acc[m].w += a * bv.w;
    }
  }
#pragma unroll
  for (int m = 0; m < 16; ++m) {
    atomicAdd(&Ct[m][c4 + 0], acc[m].x);
    atomicAdd(&Ct[m][c4 + 1], acc[m].y);
    atomicAdd(&Ct[m][c4 + 2], acc[m].z);
    atomicAdd(&Ct[m][c4 + 3], acc[m].w);
  }
  __syncthreads();
  for (int i = tid; i < 2048; i += 256) {
    int m = i >> 7;
    int h = ((i & 127) + ks * 8) & 127;
    atomicAdd(&ys[m * 1024 + n0 + h], Ct[m][h]);
  }
}

__global__ __launch_bounds__(256) void k5_out_at(const float* __restrict__ ys,
                                                 const float* __restrict__ Wp,
                                                 const float* __restrict__ be,
                                                 const float* __restrict__ gbe,
                                                 const float* __restrict__ bp,
                                                 const int* __restrict__ cnti,
                                                 float* __restrict__ out) {
  __shared__ float ytT[1024][16];
  __shared__ float Ct[16][64];
  __shared__ float sgbe[48];
  __shared__ float sinv[16];
  int tid = threadIdx.x;
  int n0 = blockIdx.x * 64;
  if (tid < 48) sgbe[tid] = gbe[tid];
  if (tid < 16) sinv[tid] = 1.0f / fmaxf(1.0f, (float)cnti[tid]);
  for (int i = tid; i < 1024; i += 256) ((float*)Ct)[i] = 0.f;
  __syncthreads();
  for (int i = tid; i < 16384; i += 256) {
    int m = i >> 10, k = i & 1023;
    ytT[k][m] = ys[m * 1024 + k] + sgbe[m * 3 + 0] * be[k] +
                sgbe[m * 3 + 1] * be[1024 + k] + sgbe[m * 3 + 2] * be[2048 + k];
  }
  __syncthreads();
  int kg = tid >> 4, nl = tid & 15;
  int h0 = nl * 4;
  float4 acc[16];
#pragma unroll
  for (int m = 0; m < 16; ++m) acc[m] = make_float4(0.f, 0.f, 0.f, 0.f);
  const float* wpp = Wp + (size_t)(kg * 64) * HH + n0 + h0;
  for (int kk = 0; kk < 64; ++kk) {
    int k = kg * 64 + kk;
    float4 bv = *(const float4*)(wpp + (size_t)kk * HH);
    const float4 y0 = *(const float4*)(&ytT[k][0]);
    const float4 y1 = *(const float4*)(&ytT[k][4]);
    const float4 y2 = *(const float4*)(&ytT[k][8]);
    const float4 y3 = *(const float4*)(&ytT[k][12]);
    acc[0].x += y0.x * bv.x;  acc[0].y += y0.x * bv.y;  acc[0].z += y0.x * bv.z;  acc[0].w += y0.x * bv.w;
    acc[1].x += y0.y * bv.x;  acc[1].y += y0.y * bv.y;  acc[1].z += y0.y * bv.z;  acc[1].w += y0.y * bv.w;
    acc[2].x += y0.z * bv.x;  acc[2].y += y0.z * bv.y;  acc[2].z += y0.z * bv.z;  acc[2].w += y0.z * bv.w;
    acc[3].x += y0.w * bv.x;  acc[3].y += y0.w * bv.y;  acc[3].z += y0.w * bv.z;  acc[3].w += y0.w * bv.w;
    acc[4].x += y1.x * bv.x;  acc[4].y += y1.x * bv.y;  acc[4].z += y1.x * bv.z;  acc[4].w += y1.x * bv.w;
    acc[5].x += y1.y * bv.x;  acc[5].y += y1.y * bv.y;  acc[5].z += y1.y * bv.z;  acc[5].w += y1.y * bv.w;
    acc[6].x += y1.z * bv.x;  acc[6].y += y1.z * bv.y;  acc[6].z += y1.z * bv.z;  acc[6].w += y1.z * bv.w;
    acc[7].x += y1.w * bv.x;  acc[7].y += y1.w * bv.y;  acc[7].z += y1.w * bv.z;  acc[7].w += y1.w * bv.w;
    acc[8].x += y2.x * bv.x;  acc[8].y += y2.x * bv.y;  acc[8].z += y2.x * bv.z;  acc[8].w += y2.x * bv.w;
    acc[9].x += y2.y * bv.x;  acc[9].y += y2.y * bv.y;  acc[9].z += y2.y * bv.z;  acc[9].w += y2.y * bv.w;
    acc[10].x += y2.z * bv.x; acc[10].y += y2.z * bv.y; acc[10].z += y2.z * bv.z; acc[10].w += y2.z * bv.w;
    acc[11].x += y2.w * bv.x; acc[11].y += y2.w * bv.y; acc[11].z += y2.w * bv.z; acc[11].w += y2.w * bv.w;
    acc[12].x += y3.x * bv.x; acc[12].y += y3.x * bv.y; acc[12].z += y3.x * bv.z; acc[12].w += y3.x * bv.w;
    acc[13].x += y3.y * bv.x; acc[13].y += y3.y * bv.y; acc[13].z += y3.y * bv.z; acc[13].w += y3.y * bv.w;
    acc[14].x += y3.z * bv.x; acc[14].y += y3.z * bv.y; acc[14].z += y3.z * bv.z; acc[14].w += y3.z * bv.w;
    acc[15].x += y3.w * bv.x; acc[15].y += y3.w * bv.y; acc[15].z += y3.w * bv.z; acc[15].w += y3.w * bv.w;
  }
#pragma unroll
  for (int m = 0; m < 16; ++m) {
    atomicAdd(&Ct[m][h0 + 0], acc[m].x);
    atomicAdd(&Ct[m][h0 + 1], acc[m].y);
    atomicAdd(&Ct[m][h0 + 2], acc[m].z);
    atomicAdd(&Ct[m][h0 + 3], acc[m].w);
  }
  __syncthreads();
  for (int i = tid; i < 1024; i += 256) {
    int m = i >> 6, h = i & 63;
    out[(size_t)m * HH + n0 + h] = (Ct[m][h] + 1536.0f * bp[n0 + h]) * sinv[m];
  }
}

// ---------------------------------------------------------------------------
extern "C" void kernel_launch(void* const* d_in, const int* in_sizes, int n_in,
                              void* d_out, int out_size, void* d_ws, size_t ws_size,
                              hipStream_t stream) {
  const float* x    = (const float*)d_in[0];
  const void*  mask = d_in[1];
  const float* wg   = (const float*)d_in[2];
  const float* We   = (const float*)d_in[3];
  const float* be   = (const float*)d_in[4];
  const float* Wp   = (const float*)d_in[5];
  const float* bp   = (const float*)d_in[6];
  float* out = (float*)d_out;
  float* wsf = (float*)d_ws;
  int*   wsi = (int*)d_ws;
  bool big = ws_size >= (size_t)OFF_BIG_END * 4;

  // zero scalar targets + z + ys (ws is not re-poisoned between replays)
  hipMemsetAsync(d_ws, 0, (size_t)OFF_ZEROEND * 4, stream);

  k0_mask<<<96, 256, 0, stream>>>(mask, wsi + OFF_CNTI);
  k1_gate<<<1536, 256, 0, stream>>>(x, wg, wsi + OFF_IDX, wsf + OFF_GVAL,
                                    wsi + OFF_HIST, wsf + OFF_GSUM,
                                    wsf + OFF_GBE);
  k2_zacc<<<1024, 256, 0, stream>>>(x, wsi + OFF_IDX, wsf + OFF_GVAL,
                                    wsf + OFF_Z);
  k3a_drops<<<96, 256, 0, stream>>>(wsi + OFF_IDX, wsf + OFF_GVAL,
                                    wsi + OFF_HIST, wsf + OFF_GSUM,
                                    wsf + OFF_GBE, wsi + OFF_DROP,
                                    wsi + OFF_NDROP, out + 65536);
  k3b_sub<<<128, 256, 0, stream>>>(x, wsf + OFF_GVAL, wsi + OFF_DROP,
                                   wsi + OFF_NDROP, wsf + OFF_Z);
  if (big) {
    k4_we<<<512, 256, 0, stream>>>(wsf + OFF_Z, We, wsf + OFF_PZ);
    k4r_red<<<64, 256, 0, stream>>>(wsf + OFF_PZ, wsf + OFF_GBE, be,
                                    wsf + OFF_YS2);
    k5_wp<<<1024, 256, 0, stream>>>(wsf + OFF_YS2, Wp, wsf + OFF_PP);
    k5r_red<<<256, 256, 0, stream>>>(wsf + OFF_PP, bp, wsi + OFF_CNTI, out);
  } else {
    k4_we_at<<<384, 256, 0, stream>>>(wsf + OFF_Z, We, wsf + OFF_YS);
    k5_out_at<<<64, 256, 0, stream>>>(wsf + OFF_YS, Wp, be, wsf + OFF_GBE, bp,
                                      wsi + OFF_CNTI, out);
  }
}